// Round 1
// baseline (720.951 us; speedup 1.0000x reference)
//
#include <hip/hip_runtime.h>
#include <math.h>

#define BATCH 8
#define SEQ   4096
#define DIM   64
#define LQ    2744            // int((1-0.33)*4096)
#define NQT   43              // ceil(2744/64)
#define QPAD  2752
#define L2E   1.4426950408889634f

// ---------------- float4 helpers ----------------
__device__ __forceinline__ float f4dot(float4 a, float4 b) {
    return fmaf(a.x, b.x, fmaf(a.y, b.y, fmaf(a.z, b.z, a.w * b.w)));
}
__device__ __forceinline__ float4 f4scale(float4 a, float s) {
    a.x *= s; a.y *= s; a.z *= s; a.w *= s; return a;
}
__device__ __forceinline__ float4 f4axpy(float p, float4 v, float4 o) {
    o.x = fmaf(p, v.x, o.x); o.y = fmaf(p, v.y, o.y);
    o.z = fmaf(p, v.z, o.z); o.w = fmaf(p, v.w, o.w); return o;
}
__device__ __forceinline__ float4 f4add(float4 a, float4 b) {
    a.x += b.x; a.y += b.y; a.z += b.z; a.w += b.w; return a;
}

// quad_perm butterfly add (stays on VALU pipe, not LDS)
template <int CTRL>
__device__ __forceinline__ float qperm_add(float v) {
    int x = __builtin_amdgcn_mov_dpp(__float_as_int(v), CTRL, 0xF, 0xF, true);
    return v + __int_as_float(x);
}

// ---------------- sortable-uint mapping ----------------
__device__ __forceinline__ unsigned f2sort(float f) {
    unsigned u = __float_as_uint(f);
    return (u & 0x80000000u) ? ~u : (u | 0x80000000u);
}
__device__ __forceinline__ float sort2f(unsigned u) {
    return __uint_as_float((u & 0x80000000u) ? (u & 0x7FFFFFFFu) : ~u);
}

// ---------------- radix select: k-th largest of 4096 (256 threads) --------
// res[0] = key of k-th largest; res[1] = #elements equal to key that are
// included among the top-k (>=1).
__device__ void radix_select_4096(const unsigned* u, int k, unsigned* hist,
                                  unsigned* res) {
    const int t = threadIdx.x;
    if (t == 0) { res[0] = 0u; res[1] = (unsigned)k; }
    for (int pass = 3; pass >= 0; --pass) {
        const int shift = pass * 8;
        for (int i = t; i < 256; i += 256) hist[i] = 0u;
        __syncthreads();
        const unsigned pref  = res[0];
        const unsigned hmask = (pass == 3) ? 0u : (0xFFFFFFFFu << (shift + 8));
        for (int i = t; i < 4096; i += 256) {
            unsigned ui = u[i];
            if ((ui & hmask) == pref) atomicAdd(&hist[(ui >> shift) & 255u], 1u);
        }
        __syncthreads();
        if (t == 0) {
            unsigned kk = res[1], cum = 0u; int bsel = 0;
            for (int bin = 255; bin >= 0; --bin) {
                if (cum + hist[bin] >= kk) { bsel = bin; res[1] = kk - cum; break; }
                cum += hist[bin];
            }
            res[0] = pref | ((unsigned)bsel << shift);
        }
        __syncthreads();
    }
}

// ---------------- K1: projections + K^T + V column-sum -------------------
__global__ __launch_bounds__(256) void proj_kernel(
    const float* __restrict__ x,  const float* __restrict__ Wq,
    const float* __restrict__ Wk, const float* __restrict__ Wv,
    float* __restrict__ Q, float* __restrict__ Km, float* __restrict__ V,
    float* __restrict__ Kt, float* __restrict__ meanacc) {
    const int rt = blockIdx.x, b = blockIdx.y, t = threadIdx.x;
    __shared__ float4 xs4[64 * 17];
    __shared__ float  red[4][64];
    {
        const float4* xg = (const float4*)(x + ((size_t)b * SEQ + rt * 64) * DIM);
        for (int i = 0; i < 4; ++i) {
            int s = t + 256 * i;
            xs4[(s >> 4) * 17 + (s & 15)] = xg[s];
        }
    }
    __syncthreads();
    const int ch = t & 63, rg = t >> 6;
    float accq[16], acck[16], accv[16];
#pragma unroll
    for (int i = 0; i < 16; ++i) { accq[i] = 0.f; acck[i] = 0.f; accv[i] = 0.f; }
    for (int dc = 0; dc < 4; ++dc) {
        float wq[16], wk[16], wv[16];
#pragma unroll
        for (int dd = 0; dd < 16; ++dd) {
            int d = dc * 16 + dd;
            wq[dd] = Wq[d * 64 + ch]; wk[dd] = Wk[d * 64 + ch]; wv[dd] = Wv[d * 64 + ch];
        }
        for (int r = 0; r < 16; ++r) {
            const int row = rg * 16 + r;
            const float4* xr = &xs4[row * 17 + dc * 4];
            float xv[16];
            float4 a0 = xr[0], a1 = xr[1], a2 = xr[2], a3 = xr[3];
            xv[0]=a0.x; xv[1]=a0.y; xv[2]=a0.z; xv[3]=a0.w;
            xv[4]=a1.x; xv[5]=a1.y; xv[6]=a1.z; xv[7]=a1.w;
            xv[8]=a2.x; xv[9]=a2.y; xv[10]=a2.z; xv[11]=a2.w;
            xv[12]=a3.x; xv[13]=a3.y; xv[14]=a3.z; xv[15]=a3.w;
#pragma unroll
            for (int dd = 0; dd < 16; ++dd) {
                accq[r] = fmaf(xv[dd], wq[dd], accq[r]);
                acck[r] = fmaf(xv[dd], wk[dd], acck[r]);
                accv[r] = fmaf(xv[dd], wv[dd], accv[r]);
            }
        }
    }
    const int rowbase = rt * 64 + rg * 16;
    float sv = 0.f;
#pragma unroll
    for (int r = 0; r < 16; ++r) {
        size_t o = ((size_t)b * SEQ + rowbase + r) * DIM + ch;
        Q[o] = accq[r]; Km[o] = acck[r]; V[o] = accv[r];
        sv += accv[r];
    }
    float4* ktp = (float4*)(Kt + ((size_t)b * 64 + ch) * SEQ + rowbase);
    ktp[0] = make_float4(acck[0], acck[1], acck[2], acck[3]);
    ktp[1] = make_float4(acck[4], acck[5], acck[6], acck[7]);
    ktp[2] = make_float4(acck[8], acck[9], acck[10], acck[11]);
    ktp[3] = make_float4(acck[12], acck[13], acck[14], acck[15]);
    red[rg][ch] = sv;
    __syncthreads();
    if (rg == 0)
        atomicAdd(&meanacc[b * 64 + ch],
                  red[0][ch] + red[1][ch] + red[2][ch] + red[3][ch]);
}

// ---------------- K2: K_reduce = mean of top-LQ per (b, ch) --------------
__global__ __launch_bounds__(256) void kmean_kernel(const float* __restrict__ Kt,
                                                    float* __restrict__ Kred) {
    __shared__ unsigned u[4096];
    __shared__ unsigned hist[256];
    __shared__ unsigned res[2];
    __shared__ float rsum[4];
    const int bc = blockIdx.x, t = threadIdx.x;
    const float4* c4 = (const float4*)(Kt + (size_t)bc * SEQ);
    for (int i = t; i < 1024; i += 256) {
        float4 v = c4[i];
        u[i*4+0] = f2sort(v.x); u[i*4+1] = f2sort(v.y);
        u[i*4+2] = f2sort(v.z); u[i*4+3] = f2sort(v.w);
    }
    __syncthreads();
    radix_select_4096(u, LQ, hist, res);
    const unsigned Tu = res[0];
    const int krem = (int)res[1];
    float loc = 0.f;
    for (int i = t; i < 4096; i += 256)
        if (u[i] > Tu) loc += sort2f(u[i]);
    for (int msk = 1; msk < 64; msk <<= 1) loc += __shfl_xor(loc, msk, 64);
    if ((t & 63) == 0) rsum[t >> 6] = loc;
    __syncthreads();
    if (t == 0) {
        float s = rsum[0] + rsum[1] + rsum[2] + rsum[3] + (float)krem * sort2f(Tu);
        Kred[bc] = s / (float)LQ;
    }
}

// ---------------- K3: sqk = K_reduce . Q ---------------------------------
__global__ __launch_bounds__(256) void sqk_kernel(const float* __restrict__ Q,
                                                  const float* __restrict__ Kred,
                                                  float* __restrict__ sqk) {
    const int b = blockIdx.y, l = blockIdx.x * 256 + threadIdx.x;
    __shared__ float kr[64];
    if (threadIdx.x < 64) kr[threadIdx.x] = Kred[b * 64 + threadIdx.x];
    __syncthreads();
    const float4* q = (const float4*)(Q + ((size_t)b * SEQ + l) * DIM);
    float s = 0.f;
#pragma unroll
    for (int i = 0; i < 16; ++i) {
        float4 v = q[i];
        s = fmaf(v.x, kr[i*4+0], s); s = fmaf(v.y, kr[i*4+1], s);
        s = fmaf(v.z, kr[i*4+2], s); s = fmaf(v.w, kr[i*4+3], s);
    }
    sqk[b * SEQ + l] = s;
}

// ---------------- K4: per-batch top-LQ index selection -------------------
__global__ __launch_bounds__(256) void select_kernel(const float* __restrict__ sqk,
                                                     int* __restrict__ sel) {
    __shared__ unsigned u[4096];
    __shared__ unsigned hist[256];
    __shared__ unsigned res[2];
    __shared__ int eq_idx[256];
    __shared__ int cnts[2];
    const int b = blockIdx.x, t = threadIdx.x;
    const float* col = sqk + (size_t)b * SEQ;
    for (int i = t; i < 4096; i += 256) u[i] = f2sort(col[i]);
    if (t < 2) cnts[t] = 0;
    __syncthreads();
    radix_select_4096(u, LQ, hist, res);
    const unsigned Tu = res[0];
    const int krem = (int)res[1];
    int* selb = sel + b * QPAD;
    for (int i = t; i < 4096; i += 256) {
        unsigned ui = u[i];
        if (ui > Tu) {
            int p = atomicAdd(&cnts[0], 1);
            selb[p] = i;
        } else if (ui == Tu) {
            int p = atomicAdd(&cnts[1], 1);
            if (p < 256) eq_idx[p] = i;
        }
    }
    __syncthreads();
    if (t == 0) {
        int ng = cnts[0];
        int ne = cnts[1] < 256 ? cnts[1] : 256;
        for (int i = 1; i < ne; ++i) {          // ascending-index sort (jax tie-break)
            int v = eq_idx[i], j = i - 1;
            while (j >= 0 && eq_idx[j] > v) { eq_idx[j+1] = eq_idx[j]; --j; }
            eq_idx[j+1] = v;
        }
        for (int j = 0; j < krem; ++j) selb[ng + j] = eq_idx[j];
        for (int j = LQ; j < QPAD; ++j) selb[j] = selb[LQ - 1];  // pad
    }
}

// ---------------- K5: fill all rows with V-mean --------------------------
__global__ __launch_bounds__(256) void fill_kernel(const float* __restrict__ meanacc,
                                                   float* __restrict__ out) {
    const int idx = blockIdx.x * 256 + threadIdx.x;       // float4 index
    if (idx >= BATCH * SEQ * 16) return;
    const int b = idx >> 16, c = idx & 15;
    const float inv = 1.0f / (float)SEQ;
    float4 mv = make_float4(meanacc[b*64 + c*4 + 0] * inv,
                            meanacc[b*64 + c*4 + 1] * inv,
                            meanacc[b*64 + c*4 + 2] * inv,
                            meanacc[b*64 + c*4 + 3] * inv);
    ((float4*)out)[idx] = mv;
}

// ---------------- K6: flash attention for selected queries ---------------
// block = 256 thr = 4 waves. lane: g = lane>>2 (query group), dq = lane&3
// (d-quarter). Lane owns queries {g, g+16, g+32, g+48}, d-range dq*16..+16.
// Wave w handles keys j ≡ slice within tile; block handles key half h.
__global__ __launch_bounds__(256) void attn_kernel(
    const float* __restrict__ Q, const float* __restrict__ Km,
    const float* __restrict__ V, const int* __restrict__ sel,
    float* __restrict__ pml, float* __restrict__ pout) {
    const int qt = blockIdx.x, h = blockIdx.y, b = blockIdx.z;
    const int t = threadIdx.x, w = t >> 6, lane = t & 63;
    const int g = lane >> 2, dq = lane & 3;

    __shared__ float4 kt4[1024];
    __shared__ float4 vt4[1024];
    __shared__ float4 qs4[64 * 17];           // query stage, reused as out-acc
    __shared__ float  pmlw[4][64][2];
    __shared__ float  fml[64][2];

    {   // stage the 64 selected query rows (gather)
        const int* selb = sel + b * QPAD;
        const int src = selb[qt * 64 + (t >> 2)];
        const float4* qg = (const float4*)(Q + ((size_t)b * SEQ + src) * DIM) + (t & 3) * 4;
        float4* dst = &qs4[(t >> 2) * 17 + (t & 3) * 4];
        dst[0] = qg[0]; dst[1] = qg[1]; dst[2] = qg[2]; dst[3] = qg[3];
    }
    __syncthreads();

    float4 qr[4][4], o4[4][4];
    float m[4], lsum[4];
#pragma unroll
    for (int qk = 0; qk < 4; ++qk) {
        const int row = g + 16 * qk;
#pragma unroll
        for (int i = 0; i < 4; ++i) {
            qr[qk][i] = f4scale(qs4[row * 17 + dq * 4 + i], 0.125f);  // 1/sqrt(64)
            o4[qk][i] = make_float4(0.f, 0.f, 0.f, 0.f);
        }
        m[qk] = -__builtin_huge_valf(); lsum[qk] = 0.f;
    }
    __syncthreads();

    const float4* Kg = (const float4*)(Km + ((size_t)b * SEQ + h * 2048) * DIM);
    const float4* Vg = (const float4*)(V  + ((size_t)b * SEQ + h * 2048) * DIM);

    for (int tile = 0; tile < 32; ++tile) {
#pragma unroll
        for (int i = 0; i < 4; ++i) {
            int s = t + 256 * i;
            kt4[s] = Kg[tile * 1024 + s];
            vt4[s] = Vg[tile * 1024 + s];
        }
        __syncthreads();
        for (int c = 0; c < 4; ++c) {
            const int j0 = w * 16 + c * 4;
            float s[4][4];
#pragma unroll
            for (int kk = 0; kk < 4; ++kk) {
                const float4* kr = &kt4[(j0 + kk) * 16 + dq * 4];
                float4 k0 = kr[0], k1 = kr[1], k2 = kr[2], k3 = kr[3];
#pragma unroll
                for (int qk = 0; qk < 4; ++qk)
                    s[kk][qk] = f4dot(qr[qk][0], k0) + f4dot(qr[qk][1], k1) +
                                f4dot(qr[qk][2], k2) + f4dot(qr[qk][3], k3);
            }
#pragma unroll
            for (int kk = 0; kk < 4; ++kk)
#pragma unroll
                for (int qk = 0; qk < 4; ++qk) {
                    float v = qperm_add<0xB1>(s[kk][qk]);   // xor 1
                    s[kk][qk] = qperm_add<0x4E>(v);         // xor 2
                }
#pragma unroll
            for (int qk = 0; qk < 4; ++qk) {
                float cm = fmaxf(fmaxf(s[0][qk], s[1][qk]), fmaxf(s[2][qk], s[3][qk]));
                if (cm > m[qk]) {
                    float f = exp2f((m[qk] - cm) * L2E);
                    lsum[qk] *= f;
                    o4[qk][0] = f4scale(o4[qk][0], f); o4[qk][1] = f4scale(o4[qk][1], f);
                    o4[qk][2] = f4scale(o4[qk][2], f); o4[qk][3] = f4scale(o4[qk][3], f);
                    m[qk] = cm;
                }
                float p0 = exp2f((s[0][qk] - m[qk]) * L2E);
                float p1 = exp2f((s[1][qk] - m[qk]) * L2E);
                float p2 = exp2f((s[2][qk] - m[qk]) * L2E);
                float p3 = exp2f((s[3][qk] - m[qk]) * L2E);
                lsum[qk] += p0 + p1 + p2 + p3;
                s[0][qk] = p0; s[1][qk] = p1; s[2][qk] = p2; s[3][qk] = p3;
            }
#pragma unroll
            for (int kk = 0; kk < 4; ++kk) {
                const float4* vr = &vt4[(j0 + kk) * 16 + dq * 4];
                float4 v0 = vr[0], v1 = vr[1], v2 = vr[2], v3 = vr[3];
#pragma unroll
                for (int qk = 0; qk < 4; ++qk) {
                    float p = s[kk][qk];
                    o4[qk][0] = f4axpy(p, v0, o4[qk][0]);
                    o4[qk][1] = f4axpy(p, v1, o4[qk][1]);
                    o4[qk][2] = f4axpy(p, v2, o4[qk][2]);
                    o4[qk][3] = f4axpy(p, v3, o4[qk][3]);
                }
            }
        }
        __syncthreads();
    }

    // ---- cross-wave combine (4 key-slices share the 64 queries) ----
    if (dq == 0) {
#pragma unroll
        for (int qk = 0; qk < 4; ++qk) {
            pmlw[w][g + 16 * qk][0] = m[qk];
            pmlw[w][g + 16 * qk][1] = lsum[qk];
        }
    }
    __syncthreads();
    float Mq[4], Lq[4];
#pragma unroll
    for (int qk = 0; qk < 4; ++qk) {
        const int q = g + 16 * qk;
        float M = fmaxf(fmaxf(pmlw[0][q][0], pmlw[1][q][0]),
                        fmaxf(pmlw[2][q][0], pmlw[3][q][0]));
        float Lt = pmlw[0][q][1] * exp2f((pmlw[0][q][0] - M) * L2E)
                 + pmlw[1][q][1] * exp2f((pmlw[1][q][0] - M) * L2E)
                 + pmlw[2][q][1] * exp2f((pmlw[2][q][0] - M) * L2E)
                 + pmlw[3][q][1] * exp2f((pmlw[3][q][0] - M) * L2E);
        float a = exp2f((m[qk] - M) * L2E);
        o4[qk][0] = f4scale(o4[qk][0], a); o4[qk][1] = f4scale(o4[qk][1], a);
        o4[qk][2] = f4scale(o4[qk][2], a); o4[qk][3] = f4scale(o4[qk][3], a);
        Mq[qk] = M; Lq[qk] = Lt;
    }
    if (w == 0 && dq == 0) {
#pragma unroll
        for (int qk = 0; qk < 4; ++qk) {
            fml[g + 16 * qk][0] = Mq[qk];
            fml[g + 16 * qk][1] = Lq[qk];
        }
    }
    for (int ww = 0; ww < 4; ++ww) {      // sequential accumulate into qs4
        if (w == ww) {
#pragma unroll
            for (int qk = 0; qk < 4; ++qk) {
                float4* ap = &qs4[(g + 16 * qk) * 17 + dq * 4];
                if (ww == 0) {
                    ap[0] = o4[qk][0]; ap[1] = o4[qk][1];
                    ap[2] = o4[qk][2]; ap[3] = o4[qk][3];
                } else {
                    ap[0] = f4add(ap[0], o4[qk][0]); ap[1] = f4add(ap[1], o4[qk][1]);
                    ap[2] = f4add(ap[2], o4[qk][2]); ap[3] = f4add(ap[3], o4[qk][3]);
                }
            }
        }
        __syncthreads();
    }
    {   // write block partial (unnormalized) + (M, L)
        const int q = t >> 2, quarter = t & 3;
        const int qs = qt * 64 + q;
        if (qs < LQ) {
            const size_t slot = (size_t)(b * 2 + h) * QPAD + qs;
            const float4* ap = &qs4[q * 17 + quarter * 4];
            float4* op = (float4*)(pout + slot * 64) + quarter * 4;
            op[0] = ap[0]; op[1] = ap[1]; op[2] = ap[2]; op[3] = ap[3];
            if (quarter == 0) {
                pml[slot * 2 + 0] = fml[q][0];
                pml[slot * 2 + 1] = fml[q][1];
            }
        }
    }
}

// ---------------- K7: merge the two key-halves, normalize, scatter -------
__global__ __launch_bounds__(256) void comb_kernel(
    const float* __restrict__ pml, const float* __restrict__ pout,
    const int* __restrict__ sel, float* __restrict__ out) {
    const int idx = blockIdx.x * 256 + threadIdx.x;   // over BATCH*LQ*16
    if (idx >= BATCH * LQ * 16) return;
    const int b = idx / (LQ * 16);
    const int r = idx % (LQ * 16);
    const int qs = r >> 4, c = r & 15;
    const size_t s0 = (size_t)(b * 2 + 0) * QPAD + qs;
    const size_t s1 = (size_t)(b * 2 + 1) * QPAD + qs;
    const float m0 = pml[s0 * 2], l0 = pml[s0 * 2 + 1];
    const float m1 = pml[s1 * 2], l1 = pml[s1 * 2 + 1];
    const float M  = fmaxf(m0, m1);
    const float e0 = exp2f((m0 - M) * L2E), e1 = exp2f((m1 - M) * L2E);
    const float inv = 1.0f / (l0 * e0 + l1 * e1);
    float4 a = ((const float4*)(pout + s0 * 64))[c];
    float4 bb = ((const float4*)(pout + s1 * 64))[c];
    float4 o = make_float4((a.x * e0 + bb.x * e1) * inv,
                           (a.y * e0 + bb.y * e1) * inv,
                           (a.z * e0 + bb.z * e1) * inv,
                           (a.w * e0 + bb.w * e1) * inv);
    const int row = sel[b * QPAD + qs];
    ((float4*)(out + ((size_t)b * SEQ + row) * DIM))[c] = o;
}

// ---------------- launcher ----------------
extern "C" void kernel_launch(void* const* d_in, const int* in_sizes, int n_in,
                              void* d_out, int out_size, void* d_ws, size_t ws_size,
                              hipStream_t stream) {
    const float* x  = (const float*)d_in[0];
    const float* Wq = (const float*)d_in[1];
    const float* Wk = (const float*)d_in[2];
    const float* Wv = (const float*)d_in[3];
    float* out = (float*)d_out;
    float* ws  = (float*)d_ws;

    float* Q       = ws;                      // 2097152
    float* Km      = Q + 2097152;             // 2097152
    float* V       = Km + 2097152;            // 2097152
    float* meanacc = V + 2097152;             // 512
    float* Kred    = meanacc + 512;           // 512
    float* sqk     = Kred + 512;              // 32768
    int*   sel     = (int*)(sqk + 32768);     // 8*2752 ints
    float* pml     = (float*)(sel + 8 * QPAD);// 8*2*2752*2
    float* pout    = pml + 8 * 2 * QPAD * 2;  // 8*2*2752*64 floats
    float* Kt      = pout;                    // alias: Kt dead before pout is written
    // total ws use ≈ 37.0 MB

    hipMemsetAsync(meanacc, 0, 512 * sizeof(float), stream);
    proj_kernel  <<<dim3(64, 8),       256, 0, stream>>>(x, Wq, Wk, Wv, Q, Km, V, Kt, meanacc);
    kmean_kernel <<<512,               256, 0, stream>>>(Kt, Kred);
    sqk_kernel   <<<dim3(16, 8),       256, 0, stream>>>(Q, Kred, sqk);
    select_kernel<<<8,                 256, 0, stream>>>(sqk, sel);
    fill_kernel  <<<2048,              256, 0, stream>>>(meanacc, out);
    attn_kernel  <<<dim3(NQT, 2, 8),   256, 0, stream>>>(Q, Km, V, sel, pml, pout);
    comb_kernel  <<<(BATCH * LQ * 16 + 255) / 256, 256, 0, stream>>>(pml, pout, sel, out);
}

// Round 2
// 291.933 us; speedup vs baseline: 2.4696x; 2.4696x over previous
//
#include <hip/hip_runtime.h>
#include <hip/hip_bf16.h>
#include <math.h>

#define BATCH 8
#define SEQ   4096
#define DIM   64
#define LQ    2744            // int((1-0.33)*4096)
#define QPB   128             // queries per attn block
#define NQB   22              // ceil(2744/128)
#define QPAD  2816            // NQB*QPB
#define KS    2               // key splits
#define L2E   1.4426950408889634f
#define QSC   0.1803368801111204f   // 0.125 * log2(e), folded into Qh

typedef _Float16 half8 __attribute__((ext_vector_type(8)));
typedef short    bs8   __attribute__((ext_vector_type(8)));
typedef float    fx16  __attribute__((ext_vector_type(16)));
typedef unsigned short ushort_t;

union UH { uint4 u4; half8 h; };
union UB { unsigned u[4]; uint4 u4; bs8 s; };

__device__ __forceinline__ unsigned pack_bf16(float a, float b) {
    __hip_bfloat162 h = __float22bfloat162_rn(make_float2(a, b));
    union { __hip_bfloat162 h; unsigned u; } cv; cv.h = h; return cv.u;
}

// ---------------- sortable-uint mapping ----------------
__device__ __forceinline__ unsigned f2sort(float f) {
    unsigned u = __float_as_uint(f);
    return (u & 0x80000000u) ? ~u : (u | 0x80000000u);
}
__device__ __forceinline__ float sort2f(unsigned u) {
    return __uint_as_float((u & 0x80000000u) ? (u & 0x7FFFFFFFu) : ~u);
}

// ---------------- radix select: k-th largest of 4096 (256 threads) --------
__device__ void radix_select_4096(const unsigned* u, int k, unsigned* hist,
                                  unsigned* res) {
    const int t = threadIdx.x;
    if (t == 0) { res[0] = 0u; res[1] = (unsigned)k; }
    for (int pass = 3; pass >= 0; --pass) {
        const int shift = pass * 8;
        for (int i = t; i < 256; i += 256) hist[i] = 0u;
        __syncthreads();
        const unsigned pref  = res[0];
        const unsigned hmask = (pass == 3) ? 0u : (0xFFFFFFFFu << (shift + 8));
        for (int i = t; i < 4096; i += 256) {
            unsigned ui = u[i];
            if ((ui & hmask) == pref) atomicAdd(&hist[(ui >> shift) & 255u], 1u);
        }
        __syncthreads();
        if (t == 0) {
            unsigned kk = res[1], cum = 0u; int bsel = 0;
            for (int bin = 255; bin >= 0; --bin) {
                if (cum + hist[bin] >= kk) { bsel = bin; res[1] = kk - cum; break; }
                cum += hist[bin];
            }
            res[0] = pref | ((unsigned)bsel << shift);
        }
        __syncthreads();
    }
}

// ---------------- K1: projections -------------------
// outputs: Q fp32 (selection path), Kt fp32 (per-channel topk path),
// Qh f16 (scaled), Kh f16, Vt bf16 transposed [b][d][k'] with k' =
// swap-bits-2,3-of-k within each 16-group (PV B-fragment order), meanacc.
__global__ __launch_bounds__(256) void proj_kernel(
    const float* __restrict__ x,  const float* __restrict__ Wq,
    const float* __restrict__ Wk, const float* __restrict__ Wv,
    float* __restrict__ Q, float* __restrict__ Kt,
    _Float16* __restrict__ Qh, _Float16* __restrict__ Kh,
    ushort_t* __restrict__ Vt, float* __restrict__ meanacc) {
    const int rt = blockIdx.x, b = blockIdx.y, t = threadIdx.x;
    __shared__ float4 xs4[64 * 17];
    __shared__ float  red[4][64];
    {
        const float4* xg = (const float4*)(x + ((size_t)b * SEQ + rt * 64) * DIM);
        for (int i = 0; i < 4; ++i) {
            int s = t + 256 * i;
            xs4[(s >> 4) * 17 + (s & 15)] = xg[s];
        }
    }
    __syncthreads();
    const int ch = t & 63, rg = t >> 6;
    float accq[16], acck[16], accv[16];
#pragma unroll
    for (int i = 0; i < 16; ++i) { accq[i] = 0.f; acck[i] = 0.f; accv[i] = 0.f; }
    for (int dc = 0; dc < 4; ++dc) {
        float wq[16], wk[16], wv[16];
#pragma unroll
        for (int dd = 0; dd < 16; ++dd) {
            int d = dc * 16 + dd;
            wq[dd] = Wq[d * 64 + ch]; wk[dd] = Wk[d * 64 + ch]; wv[dd] = Wv[d * 64 + ch];
        }
        for (int r = 0; r < 16; ++r) {
            const int row = rg * 16 + r;
            const float4* xr = &xs4[row * 17 + dc * 4];
            float xv[16];
            float4 a0 = xr[0], a1 = xr[1], a2 = xr[2], a3 = xr[3];
            xv[0]=a0.x; xv[1]=a0.y; xv[2]=a0.z; xv[3]=a0.w;
            xv[4]=a1.x; xv[5]=a1.y; xv[6]=a1.z; xv[7]=a1.w;
            xv[8]=a2.x; xv[9]=a2.y; xv[10]=a2.z; xv[11]=a2.w;
            xv[12]=a3.x; xv[13]=a3.y; xv[14]=a3.z; xv[15]=a3.w;
#pragma unroll
            for (int dd = 0; dd < 16; ++dd) {
                accq[r] = fmaf(xv[dd], wq[dd], accq[r]);
                acck[r] = fmaf(xv[dd], wk[dd], acck[r]);
                accv[r] = fmaf(xv[dd], wv[dd], accv[r]);
            }
        }
    }
    const int rowbase = rt * 64 + rg * 16;
    float sv = 0.f;
#pragma unroll
    for (int r = 0; r < 16; ++r) {
        size_t o = ((size_t)b * SEQ + rowbase + r) * DIM + ch;
        Q[o]  = accq[r];
        Qh[o] = (_Float16)(accq[r] * QSC);
        Kh[o] = (_Float16)acck[r];
        sv += accv[r];
    }
    // Kt fp32 (for per-channel top-k)
    float4* ktp = (float4*)(Kt + ((size_t)b * 64 + ch) * SEQ + rowbase);
    ktp[0] = make_float4(acck[0], acck[1], acck[2], acck[3]);
    ktp[1] = make_float4(acck[4], acck[5], acck[6], acck[7]);
    ktp[2] = make_float4(acck[8], acck[9], acck[10], acck[11]);
    ktp[3] = make_float4(acck[12], acck[13], acck[14], acck[15]);
    // Vt bf16, k-permuted pair order within the 16-group: [0,1,4,5,2,3,6,7]
    {
        unsigned pk[8];
#pragma unroll
        for (int i = 0; i < 8; ++i) pk[i] = pack_bf16(accv[2*i], accv[2*i+1]);
        uint4* vp = (uint4*)(Vt + ((size_t)(b * 64 + ch)) * SEQ + rowbase);
        vp[0] = make_uint4(pk[0], pk[1], pk[4], pk[5]);
        vp[1] = make_uint4(pk[2], pk[3], pk[6], pk[7]);
    }
    red[rg][ch] = sv;
    __syncthreads();
    if (rg == 0)
        atomicAdd(&meanacc[b * 64 + ch],
                  red[0][ch] + red[1][ch] + red[2][ch] + red[3][ch]);
}

// ---------------- K2: K_reduce = mean of top-LQ per (b, ch) --------------
__global__ __launch_bounds__(256) void kmean_kernel(const float* __restrict__ Kt,
                                                    float* __restrict__ Kred) {
    __shared__ unsigned u[4096];
    __shared__ unsigned hist[256];
    __shared__ unsigned res[2];
    __shared__ float rsum[4];
    const int bc = blockIdx.x, t = threadIdx.x;
    const float4* c4 = (const float4*)(Kt + (size_t)bc * SEQ);
    for (int i = t; i < 1024; i += 256) {
        float4 v = c4[i];
        u[i*4+0] = f2sort(v.x); u[i*4+1] = f2sort(v.y);
        u[i*4+2] = f2sort(v.z); u[i*4+3] = f2sort(v.w);
    }
    __syncthreads();
    radix_select_4096(u, LQ, hist, res);
    const unsigned Tu = res[0];
    const int krem = (int)res[1];
    float loc = 0.f;
    for (int i = t; i < 4096; i += 256)
        if (u[i] > Tu) loc += sort2f(u[i]);
    for (int msk = 1; msk < 64; msk <<= 1) loc += __shfl_xor(loc, msk, 64);
    if ((t & 63) == 0) rsum[t >> 6] = loc;
    __syncthreads();
    if (t == 0) {
        float s = rsum[0] + rsum[1] + rsum[2] + rsum[3] + (float)krem * sort2f(Tu);
        Kred[bc] = s / (float)LQ;
    }
}

// ---------------- K3: sqk = K_reduce . Q (fp32, selection-exact) ---------
__global__ __launch_bounds__(256) void sqk_kernel(const float* __restrict__ Q,
                                                  const float* __restrict__ Kred,
                                                  float* __restrict__ sqk) {
    const int b = blockIdx.y, l = blockIdx.x * 256 + threadIdx.x;
    __shared__ float kr[64];
    if (threadIdx.x < 64) kr[threadIdx.x] = Kred[b * 64 + threadIdx.x];
    __syncthreads();
    const float4* q = (const float4*)(Q + ((size_t)b * SEQ + l) * DIM);
    float s = 0.f;
#pragma unroll
    for (int i = 0; i < 16; ++i) {
        float4 v = q[i];
        s = fmaf(v.x, kr[i*4+0], s); s = fmaf(v.y, kr[i*4+1], s);
        s = fmaf(v.z, kr[i*4+2], s); s = fmaf(v.w, kr[i*4+3], s);
    }
    sqk[b * SEQ + l] = s;
}

// ---------------- K4: per-batch top-LQ index selection -------------------
__global__ __launch_bounds__(256) void select_kernel(const float* __restrict__ sqk,
                                                     int* __restrict__ sel) {
    __shared__ unsigned u[4096];
    __shared__ unsigned hist[256];
    __shared__ unsigned res[2];
    __shared__ int eq_idx[256];
    __shared__ int cnts[2];
    const int b = blockIdx.x, t = threadIdx.x;
    const float* col = sqk + (size_t)b * SEQ;
    for (int i = t; i < 4096; i += 256) u[i] = f2sort(col[i]);
    if (t < 2) cnts[t] = 0;
    __syncthreads();
    radix_select_4096(u, LQ, hist, res);
    const unsigned Tu = res[0];
    const int krem = (int)res[1];
    int* selb = sel + b * QPAD;
    for (int i = t; i < 4096; i += 256) {
        unsigned ui = u[i];
        if (ui > Tu) {
            int p = atomicAdd(&cnts[0], 1);
            selb[p] = i;
        } else if (ui == Tu) {
            int p = atomicAdd(&cnts[1], 1);
            if (p < 256) eq_idx[p] = i;
        }
    }
    __syncthreads();
    if (t == 0) {
        int ng = cnts[0];
        int ne = cnts[1] < 256 ? cnts[1] : 256;
        for (int i = 1; i < ne; ++i) {
            int v = eq_idx[i], j = i - 1;
            while (j >= 0 && eq_idx[j] > v) { eq_idx[j+1] = eq_idx[j]; --j; }
            eq_idx[j+1] = v;
        }
        for (int j = 0; j < krem; ++j) selb[ng + j] = eq_idx[j];
        for (int j = LQ; j < QPAD; ++j) selb[j] = selb[LQ - 1];
    }
}

// ---------------- K5: fill all rows with V-mean --------------------------
__global__ __launch_bounds__(256) void fill_kernel(const float* __restrict__ meanacc,
                                                   float* __restrict__ out) {
    const int idx = blockIdx.x * 256 + threadIdx.x;
    if (idx >= BATCH * SEQ * 16) return;
    const int b = idx >> 16, c = idx & 15;
    const float inv = 1.0f / (float)SEQ;
    float4 mv = make_float4(meanacc[b*64 + c*4 + 0] * inv,
                            meanacc[b*64 + c*4 + 1] * inv,
                            meanacc[b*64 + c*4 + 2] * inv,
                            meanacc[b*64 + c*4 + 3] * inv);
    ((float4*)out)[idx] = mv;
}

// ---------------- K6: MFMA flash attention (no-max online softmax) -------
// Wave: 32 queries (col=lane&31) x 2048 keys. Block: 4 waves, shared
// double-buffered K/V tiles (32 keys each). S^T via mfma f16 (col=q ->
// per-lane softmax state); PV via mfma bf16 with k-permutation folded
// into the Vt global layout (every fragment = one ds_read_b128).
// LDS rows are 128B with 16B-granule XOR swizzle (4-way conflicts max).
__global__ __launch_bounds__(256) void attn_kernel(
    const ushort_t* __restrict__ Qh, const ushort_t* __restrict__ Kh,
    const ushort_t* __restrict__ Vt, const int* __restrict__ sel,
    float* __restrict__ pml, float* __restrict__ pout) {
    const int qt = blockIdx.x, ks = blockIdx.y, b = blockIdx.z;
    const int t = threadIdx.x, w = t >> 6, lane = t & 63;
    const int col = lane & 31, h = lane >> 5;

    __shared__ ushort_t Ktile[2][32 * 64];  // row k: 64 halves, swizzled granules
    __shared__ ushort_t Vtile[2][32 * 64];  // row r: [d=r | d=r+32], swizzled

    // persistent Q fragments (B-operand: lane holds q=col, d=16m+8h+j)
    half8 qf[4];
    {
        const int q = qt * QPB + w * 32 + col;
        const int row = sel[b * QPAD + q];
        const uint4* qg = (const uint4*)(Qh + ((size_t)b * SEQ + row) * DIM);
#pragma unroll
        for (int m = 0; m < 4; ++m) { UH u; u.u4 = qg[2 * m + h]; qf[m] = u.h; }
    }

    fx16 O0, O1;
#pragma unroll
    for (int r = 0; r < 16; ++r) { O0[r] = 0.f; O1[r] = 0.f; }
    float l = 0.f;

    // staging assignment: thread -> (row, stored granule); logical granule
    // lg = sgr ^ (row&7)
    const int srow = t >> 3, sgr = t & 7;
    const int lg = sgr ^ (srow & 7);
    const int vD = lg >> 2, vc = (lg >> 1) & 1, vh = lg & 1;
    const size_t kgbase = ((size_t)b * SEQ + ks * 2048 + srow) * DIM + 8 * lg;
    const size_t vgbase = ((size_t)(b * DIM + srow + 32 * vD)) * SEQ
                          + ks * 2048 + vc * 16 + vh * 8;

    uint4 kreg = *(const uint4*)(Kh + kgbase);
    uint4 vreg = *(const uint4*)(Vt + vgbase);

    for (int tile = 0; tile < 64; ++tile) {
        const int buf = tile & 1;
        *(uint4*)&Ktile[buf][srow * 64 + sgr * 8] = kreg;
        *(uint4*)&Vtile[buf][srow * 64 + sgr * 8] = vreg;
        __syncthreads();
        if (tile < 63) {   // prefetch next tile during compute
            kreg = *(const uint4*)(Kh + kgbase + (size_t)(tile + 1) * 32 * DIM);
            vreg = *(const uint4*)(Vt + vgbase + (size_t)(tile + 1) * 32);
        }
        // S^T = K * Q^T  (f16 MFMA, fp32 acc); Qh pre-scaled by 0.125*log2e
        fx16 S;
#pragma unroll
        for (int r = 0; r < 16; ++r) S[r] = 0.f;
#pragma unroll
        for (int m = 0; m < 4; ++m) {
            UH kf;
            kf.u4 = *(const uint4*)&Ktile[buf][col * 64 + 8 * ((2 * m + h) ^ (col & 7))];
            S = __builtin_amdgcn_mfma_f32_32x32x16_f16(kf.h, qf[m], S, 0, 0, 0);
        }
        // softmax numerators (no max subtraction: |s|*log2e bounded « 88)
        float p[16];
#pragma unroll
        for (int r = 0; r < 16; ++r) p[r] = exp2f(S[r]);
#pragma unroll
        for (int r = 0; r < 16; ++r) l += p[r];
        // pack P to bf16 A-fragments (C-reg order == A-slot order by the
        // k-permutation folded into Vt)
        UB A0, A1;
#pragma unroll
        for (int v = 0; v < 4; ++v) {
            A0.u[v] = pack_bf16(p[2 * v],     p[2 * v + 1]);
            A1.u[v] = pack_bf16(p[8 + 2 * v], p[8 + 2 * v + 1]);
        }
        // O += P * V  (bf16 MFMA)
#pragma unroll
        for (int D = 0; D < 2; ++D) {
            fx16& O = D ? O1 : O0;
#pragma unroll
            for (int c = 0; c < 2; ++c) {
                UB vf;
                vf.u4 = *(const uint4*)&Vtile[buf][col * 64 + 8 * ((4 * D + 2 * c + h) ^ (col & 7))];
                O = __builtin_amdgcn_mfma_f32_32x32x16_bf16(c ? A1.s : A0.s, vf.s, O, 0, 0, 0);
            }
        }
    }

    l += __shfl_xor(l, 32);   // combine the two k-halves of the column sum

    const int qg0 = qt * QPB + w * 32;
    const size_t slot = (size_t)(b * KS + ks) * QPAD;
#pragma unroll
    for (int D = 0; D < 2; ++D) {
        const fx16& O = D ? O1 : O0;
#pragma unroll
        for (int r = 0; r < 16; ++r) {
            const int q = (r & 3) + 8 * (r >> 2) + 4 * h;
            pout[(slot + qg0 + q) * DIM + D * 32 + col] = O[r];
        }
    }
    if (h == 0) pml[slot + qg0 + col] = l;
}

// ---------------- K7: merge key-splits, normalize, scatter ---------------
__global__ __launch_bounds__(256) void comb_kernel(
    const float* __restrict__ pml, const float* __restrict__ pout,
    const int* __restrict__ sel, float* __restrict__ out) {
    const int idx = blockIdx.x * 256 + threadIdx.x;
    if (idx >= BATCH * LQ * 16) return;
    const int b = idx / (LQ * 16);
    const int r = idx % (LQ * 16);
    const int qs = r >> 4, c = r & 15;
    const size_t s0 = (size_t)(b * KS + 0) * QPAD + qs;
    const size_t s1 = (size_t)(b * KS + 1) * QPAD + qs;
    const float inv = 1.0f / (pml[s0] + pml[s1]);
    float4 a  = ((const float4*)(pout + s0 * DIM))[c];
    float4 bb = ((const float4*)(pout + s1 * DIM))[c];
    float4 o = make_float4((a.x + bb.x) * inv, (a.y + bb.y) * inv,
                           (a.z + bb.z) * inv, (a.w + bb.w) * inv);
    const int row = sel[b * QPAD + qs];
    ((float4*)(out + ((size_t)b * SEQ + row) * DIM))[c] = o;
}

// ---------------- launcher ----------------
extern "C" void kernel_launch(void* const* d_in, const int* in_sizes, int n_in,
                              void* d_out, int out_size, void* d_ws, size_t ws_size,
                              hipStream_t stream) {
    const float* x  = (const float*)d_in[0];
    const float* Wq = (const float*)d_in[1];
    const float* Wk = (const float*)d_in[2];
    const float* Wv = (const float*)d_in[3];
    float* out = (float*)d_out;
    char* wsb  = (char*)d_ws;

    // workspace layout (bytes), total ~31.4 MB
    float*    Q       = (float*)(wsb);                 //  8,388,608
    _Float16* Qh      = (_Float16*)(wsb + 8388608);    //  4,194,304
    _Float16* Kh      = (_Float16*)(wsb + 12582912);   //  4,194,304
    ushort_t* Vt      = (ushort_t*)(wsb + 16777216);   //  4,194,304
    float*    meanacc = (float*)(wsb + 20971520);      //  2,048
    float*    Kred    = (float*)(wsb + 20973568);      //  2,048
    float*    sqk     = (float*)(wsb + 20975616);      //  131,072
    int*      sel     = (int*)(wsb + 21106688);        //  90,112
    float*    pml     = (float*)(wsb + 21196800);      //  180,224
    float*    pout    = (float*)(wsb + 21377024);      // 11,534,336
    float*    Kt      = pout;  // alias: Kt dead before attn writes pout

    hipMemsetAsync(meanacc, 0, 512 * sizeof(float), stream);
    proj_kernel  <<<dim3(64, 8),          256, 0, stream>>>(x, Wq, Wk, Wv, Q, Kt,
                                                            Qh, Kh, Vt, meanacc);
    kmean_kernel <<<512,                  256, 0, stream>>>(Kt, Kred);
    sqk_kernel   <<<dim3(16, 8),          256, 0, stream>>>(Q, Kred, sqk);
    select_kernel<<<8,                    256, 0, stream>>>(sqk, sel);
    fill_kernel  <<<2048,                 256, 0, stream>>>(meanacc, out);
    attn_kernel  <<<dim3(NQB, KS, BATCH), 256, 0, stream>>>((const ushort_t*)Qh,
                                                            (const ushort_t*)Kh,
                                                            Vt, sel, pml, pout);
    comb_kernel  <<<1372,                 256, 0, stream>>>(pml, pout, sel, out);
}

// Round 3
// 201.963 us; speedup vs baseline: 3.5697x; 1.4455x over previous
//
#include <hip/hip_runtime.h>
#include <hip/hip_bf16.h>
#include <math.h>

#define BATCH 8
#define SEQ   4096
#define DIM   64
#define LQ    2744            // int((1-0.33)*4096)
#define QPB   128             // queries per attn block
#define NQB   22              // ceil(2744/128)
#define QPAD  2816            // NQB*QPB
#define KS    4               // key splits (1024 keys per block)
#define L2E   1.4426950408889634f
#define QSC   0.1803368801111204f   // 0.125 * log2(e), folded into Qh

typedef _Float16 half8 __attribute__((ext_vector_type(8)));
typedef short    bs8   __attribute__((ext_vector_type(8)));
typedef float    fx16  __attribute__((ext_vector_type(16)));
typedef unsigned short ushort_t;

union UH { uint4 u4; half8 h; };
union UB { unsigned u[4]; uint4 u4; bs8 s; };

__device__ __forceinline__ unsigned pack_bf16(float a, float b) {
    __hip_bfloat162 h = __float22bfloat162_rn(make_float2(a, b));
    union { __hip_bfloat162 h; unsigned u; } cv; cv.h = h; return cv.u;
}

// ---------------- sortable-uint mapping ----------------
__device__ __forceinline__ unsigned f2sort(float f) {
    unsigned u = __float_as_uint(f);
    return (u & 0x80000000u) ? ~u : (u | 0x80000000u);
}
__device__ __forceinline__ float sort2f(unsigned u) {
    return __uint_as_float((u & 0x80000000u) ? (u & 0x7FFFFFFFu) : ~u);
}

// ---------------- radix select, parallel scan (256 threads) --------------
// res[0] = key of k-th largest; res[1] = #elements equal to key included
// among the top-k. Serial thread-0 bin scan replaced by 256-thread
// Hillis-Steele suffix sum (8 steps) — removes the per-pass serial chain.
__device__ void radix_select_4096(const unsigned* u, int k, unsigned* hist,
                                  unsigned* scan, unsigned* res) {
    const int t = threadIdx.x;
    if (t == 0) { res[0] = 0u; res[1] = (unsigned)k; }
    for (int pass = 3; pass >= 0; --pass) {
        const int shift = pass * 8;
        hist[t] = 0u;
        __syncthreads();
        const unsigned pref  = res[0];
        const unsigned kk    = res[1];     // read BEFORE anyone rewrites res
        const unsigned hmask = (pass == 3) ? 0u : (0xFFFFFFFFu << (shift + 8));
        for (int i = t; i < 4096; i += 256) {
            unsigned ui = u[i];
            if ((ui & hmask) == pref) atomicAdd(&hist[(ui >> shift) & 255u], 1u);
        }
        __syncthreads();
        const unsigned h = hist[t];
        unsigned s = h;
        scan[t] = s;
        __syncthreads();
#pragma unroll
        for (int ofs = 1; ofs < 256; ofs <<= 1) {
            unsigned add = (t + ofs < 256) ? scan[t + ofs] : 0u;
            __syncthreads();
            s += add;
            scan[t] = s;
            __syncthreads();
        }
        // s = inclusive suffix sum hist[t..255]; unique threshold bin:
        if (s >= kk && (s - h) < kk) {
            res[0] = pref | ((unsigned)t << shift);
            res[1] = kk - (s - h);
        }
        __syncthreads();
    }
}

// ---------------- K1: projections -------------------
__global__ __launch_bounds__(256) void proj_kernel(
    const float* __restrict__ x,  const float* __restrict__ Wq,
    const float* __restrict__ Wk, const float* __restrict__ Wv,
    float* __restrict__ Q, float* __restrict__ Kt,
    _Float16* __restrict__ Qh, _Float16* __restrict__ Kh,
    ushort_t* __restrict__ Vt, float* __restrict__ meanacc) {
    const int rt = blockIdx.x, b = blockIdx.y, t = threadIdx.x;
    __shared__ float4 xs4[64 * 17];
    __shared__ float  red[4][64];
    {
        const float4* xg = (const float4*)(x + ((size_t)b * SEQ + rt * 64) * DIM);
        for (int i = 0; i < 4; ++i) {
            int s = t + 256 * i;
            xs4[(s >> 4) * 17 + (s & 15)] = xg[s];
        }
    }
    __syncthreads();
    const int ch = t & 63, rg = t >> 6;
    float accq[16], acck[16], accv[16];
#pragma unroll
    for (int i = 0; i < 16; ++i) { accq[i] = 0.f; acck[i] = 0.f; accv[i] = 0.f; }
    for (int dc = 0; dc < 4; ++dc) {
        float wq[16], wk[16], wv[16];
#pragma unroll
        for (int dd = 0; dd < 16; ++dd) {
            int d = dc * 16 + dd;
            wq[dd] = Wq[d * 64 + ch]; wk[dd] = Wk[d * 64 + ch]; wv[dd] = Wv[d * 64 + ch];
        }
        for (int r = 0; r < 16; ++r) {
            const int row = rg * 16 + r;
            const float4* xr = &xs4[row * 17 + dc * 4];
            float xv[16];
            float4 a0 = xr[0], a1 = xr[1], a2 = xr[2], a3 = xr[3];
            xv[0]=a0.x; xv[1]=a0.y; xv[2]=a0.z; xv[3]=a0.w;
            xv[4]=a1.x; xv[5]=a1.y; xv[6]=a1.z; xv[7]=a1.w;
            xv[8]=a2.x; xv[9]=a2.y; xv[10]=a2.z; xv[11]=a2.w;
            xv[12]=a3.x; xv[13]=a3.y; xv[14]=a3.z; xv[15]=a3.w;
#pragma unroll
            for (int dd = 0; dd < 16; ++dd) {
                accq[r] = fmaf(xv[dd], wq[dd], accq[r]);
                acck[r] = fmaf(xv[dd], wk[dd], acck[r]);
                accv[r] = fmaf(xv[dd], wv[dd], accv[r]);
            }
        }
    }
    const int rowbase = rt * 64 + rg * 16;
    float sv = 0.f;
#pragma unroll
    for (int r = 0; r < 16; ++r) {
        size_t o = ((size_t)b * SEQ + rowbase + r) * DIM + ch;
        Q[o]  = accq[r];
        Qh[o] = (_Float16)(accq[r] * QSC);
        Kh[o] = (_Float16)acck[r];
        sv += accv[r];
    }
    float4* ktp = (float4*)(Kt + ((size_t)b * 64 + ch) * SEQ + rowbase);
    ktp[0] = make_float4(acck[0], acck[1], acck[2], acck[3]);
    ktp[1] = make_float4(acck[4], acck[5], acck[6], acck[7]);
    ktp[2] = make_float4(acck[8], acck[9], acck[10], acck[11]);
    ktp[3] = make_float4(acck[12], acck[13], acck[14], acck[15]);
    // Vt bf16, k-permuted pair order within each 16-group: [0,1,4,5,2,3,6,7]
    {
        unsigned pk[8];
#pragma unroll
        for (int i = 0; i < 8; ++i) pk[i] = pack_bf16(accv[2*i], accv[2*i+1]);
        uint4* vp = (uint4*)(Vt + ((size_t)(b * 64 + ch)) * SEQ + rowbase);
        vp[0] = make_uint4(pk[0], pk[1], pk[4], pk[5]);
        vp[1] = make_uint4(pk[2], pk[3], pk[6], pk[7]);
    }
    red[rg][ch] = sv;
    __syncthreads();
    if (rg == 0)
        atomicAdd(&meanacc[b * 64 + ch],
                  red[0][ch] + red[1][ch] + red[2][ch] + red[3][ch]);
}

// ---------------- K2: K_reduce = mean of top-LQ per (b, ch) --------------
__global__ __launch_bounds__(256) void kmean_kernel(const float* __restrict__ Kt,
                                                    float* __restrict__ Kred) {
    __shared__ unsigned u[4096];
    __shared__ unsigned hist[256];
    __shared__ unsigned scan[256];
    __shared__ unsigned res[2];
    __shared__ float rsum[4];
    const int bc = blockIdx.x, t = threadIdx.x;
    const float4* c4 = (const float4*)(Kt + (size_t)bc * SEQ);
    for (int i = t; i < 1024; i += 256) {
        float4 v = c4[i];
        u[i*4+0] = f2sort(v.x); u[i*4+1] = f2sort(v.y);
        u[i*4+2] = f2sort(v.z); u[i*4+3] = f2sort(v.w);
    }
    __syncthreads();
    radix_select_4096(u, LQ, hist, scan, res);
    const unsigned Tu = res[0];
    const int krem = (int)res[1];
    float loc = 0.f;
    for (int i = t; i < 4096; i += 256)
        if (u[i] > Tu) loc += sort2f(u[i]);
    for (int msk = 1; msk < 64; msk <<= 1) loc += __shfl_xor(loc, msk, 64);
    if ((t & 63) == 0) rsum[t >> 6] = loc;
    __syncthreads();
    if (t == 0) {
        float s = rsum[0] + rsum[1] + rsum[2] + rsum[3] + (float)krem * sort2f(Tu);
        Kred[bc] = s / (float)LQ;
    }
}

// ---------------- K3: sqk = K_reduce . Q (fp32, selection-exact) ---------
__global__ __launch_bounds__(256) void sqk_kernel(const float* __restrict__ Q,
                                                  const float* __restrict__ Kred,
                                                  float* __restrict__ sqk) {
    const int b = blockIdx.y, l = blockIdx.x * 256 + threadIdx.x;
    __shared__ float kr[64];
    if (threadIdx.x < 64) kr[threadIdx.x] = Kred[b * 64 + threadIdx.x];
    __syncthreads();
    const float4* q = (const float4*)(Q + ((size_t)b * SEQ + l) * DIM);
    float s = 0.f;
#pragma unroll
    for (int i = 0; i < 16; ++i) {
        float4 v = q[i];
        s = fmaf(v.x, kr[i*4+0], s); s = fmaf(v.y, kr[i*4+1], s);
        s = fmaf(v.z, kr[i*4+2], s); s = fmaf(v.w, kr[i*4+3], s);
    }
    sqk[b * SEQ + l] = s;
}

// ---------------- K4: per-batch top-LQ index selection -------------------
__global__ __launch_bounds__(256) void select_kernel(const float* __restrict__ sqk,
                                                     int* __restrict__ sel) {
    __shared__ unsigned u[4096];
    __shared__ unsigned hist[256];
    __shared__ unsigned scan[256];
    __shared__ unsigned res[2];
    __shared__ int eq_idx[256];
    __shared__ int cnts[2];
    const int b = blockIdx.x, t = threadIdx.x;
    const float* col = sqk + (size_t)b * SEQ;
    for (int i = t; i < 4096; i += 256) u[i] = f2sort(col[i]);
    if (t < 2) cnts[t] = 0;
    __syncthreads();
    radix_select_4096(u, LQ, hist, scan, res);
    const unsigned Tu = res[0];
    const int krem = (int)res[1];
    int* selb = sel + b * QPAD;
    for (int i = t; i < 4096; i += 256) {
        unsigned ui = u[i];
        if (ui > Tu) {
            int p = atomicAdd(&cnts[0], 1);
            selb[p] = i;
        } else if (ui == Tu) {
            int p = atomicAdd(&cnts[1], 1);
            if (p < 256) eq_idx[p] = i;
        }
    }
    __syncthreads();
    if (t == 0) {
        int ng = cnts[0];
        int ne = cnts[1] < 256 ? cnts[1] : 256;
        for (int i = 1; i < ne; ++i) {          // ties are ~unique floats: ne≈1
            int v = eq_idx[i], j = i - 1;
            while (j >= 0 && eq_idx[j] > v) { eq_idx[j+1] = eq_idx[j]; --j; }
            eq_idx[j+1] = v;
        }
        for (int j = 0; j < krem; ++j) selb[ng + j] = eq_idx[j];
        for (int j = LQ; j < QPAD; ++j) selb[j] = selb[LQ - 1];
    }
}

// ---------------- K5: fill all rows with V-mean --------------------------
__global__ __launch_bounds__(256) void fill_kernel(const float* __restrict__ meanacc,
                                                   float* __restrict__ out) {
    const int idx = blockIdx.x * 256 + threadIdx.x;
    if (idx >= BATCH * SEQ * 16) return;
    const int b = idx >> 16, c = idx & 15;
    const float inv = 1.0f / (float)SEQ;
    float4 mv = make_float4(meanacc[b*64 + c*4 + 0] * inv,
                            meanacc[b*64 + c*4 + 1] * inv,
                            meanacc[b*64 + c*4 + 2] * inv,
                            meanacc[b*64 + c*4 + 3] * inv);
    ((float4*)out)[idx] = mv;
}

// ---------------- K6: MFMA flash attention (no-max online softmax) -------
// KS=4 key splits -> grid 704 blocks (~2.75/CU) for cross-wave latency
// hiding. Partials are plain sums (no running max), so key-split merge is
// global fp32 atomicAdd into zeroed pout/pl.
__global__ __launch_bounds__(256) void attn_kernel(
    const ushort_t* __restrict__ Qh, const ushort_t* __restrict__ Kh,
    const ushort_t* __restrict__ Vt, const int* __restrict__ sel,
    float* __restrict__ pl, float* __restrict__ pout) {
    const int qt = blockIdx.x, ks = blockIdx.y, b = blockIdx.z;
    const int t = threadIdx.x, w = t >> 6, lane = t & 63;
    const int col = lane & 31, h = lane >> 5;

    __shared__ ushort_t Ktile[2][32 * 64];
    __shared__ ushort_t Vtile[2][32 * 64];

    // persistent Q fragments (B-operand: lane holds q=col, d=16m+8h+j)
    half8 qf[4];
    {
        const int q = qt * QPB + w * 32 + col;
        const int row = sel[b * QPAD + q];
        const uint4* qg = (const uint4*)(Qh + ((size_t)b * SEQ + row) * DIM);
#pragma unroll
        for (int m = 0; m < 4; ++m) { UH u; u.u4 = qg[2 * m + h]; qf[m] = u.h; }
    }

    fx16 O0, O1;
#pragma unroll
    for (int r = 0; r < 16; ++r) { O0[r] = 0.f; O1[r] = 0.f; }
    float l = 0.f;

    const int srow = t >> 3, sgr = t & 7;
    const int lg = sgr ^ (srow & 7);
    const int vD = lg >> 2, vc = (lg >> 1) & 1, vh = lg & 1;
    const size_t kgbase = ((size_t)b * SEQ + ks * 1024 + srow) * DIM + 8 * lg;
    const size_t vgbase = ((size_t)(b * DIM + srow + 32 * vD)) * SEQ
                          + ks * 1024 + vc * 16 + vh * 8;

    uint4 kreg = *(const uint4*)(Kh + kgbase);
    uint4 vreg = *(const uint4*)(Vt + vgbase);

    for (int tile = 0; tile < 32; ++tile) {
        const int buf = tile & 1;
        *(uint4*)&Ktile[buf][srow * 64 + sgr * 8] = kreg;
        *(uint4*)&Vtile[buf][srow * 64 + sgr * 8] = vreg;
        __syncthreads();
        if (tile < 31) {   // prefetch next tile during compute
            kreg = *(const uint4*)(Kh + kgbase + (size_t)(tile + 1) * 32 * DIM);
            vreg = *(const uint4*)(Vt + vgbase + (size_t)(tile + 1) * 32);
        }
        // S^T = K * Q^T  (f16 MFMA); Qh pre-scaled by 0.125*log2e
        fx16 S;
#pragma unroll
        for (int r = 0; r < 16; ++r) S[r] = 0.f;
#pragma unroll
        for (int m = 0; m < 4; ++m) {
            UH kf;
            kf.u4 = *(const uint4*)&Ktile[buf][col * 64 + 8 * ((2 * m + h) ^ (col & 7))];
            S = __builtin_amdgcn_mfma_f32_32x32x16_f16(kf.h, qf[m], S, 0, 0, 0);
        }
        // softmax numerators (no max subtraction: scores bounded « 128)
        float p[16];
#pragma unroll
        for (int r = 0; r < 16; ++r) p[r] = exp2f(S[r]);
#pragma unroll
        for (int r = 0; r < 16; ++r) l += p[r];
        UB A0, A1;
#pragma unroll
        for (int v = 0; v < 4; ++v) {
            A0.u[v] = pack_bf16(p[2 * v],     p[2 * v + 1]);
            A1.u[v] = pack_bf16(p[8 + 2 * v], p[8 + 2 * v + 1]);
        }
        // O += P * V  (bf16 MFMA)
#pragma unroll
        for (int D = 0; D < 2; ++D) {
            fx16& O = D ? O1 : O0;
#pragma unroll
            for (int c = 0; c < 2; ++c) {
                UB vf;
                vf.u4 = *(const uint4*)&Vtile[buf][col * 64 + 8 * ((4 * D + 2 * c + h) ^ (col & 7))];
                O = __builtin_amdgcn_mfma_f32_32x32x16_bf16(c ? A1.s : A0.s, vf.s, O, 0, 0, 0);
            }
        }
    }

    l += __shfl_xor(l, 32);   // combine the two k-halves of the column sum

    const int qg0 = qt * QPB + w * 32;
    const size_t base = (size_t)b * QPAD + qg0;
#pragma unroll
    for (int D = 0; D < 2; ++D) {
        const fx16& O = D ? O1 : O0;
#pragma unroll
        for (int r = 0; r < 16; ++r) {
            const int q = (r & 3) + 8 * (r >> 2) + 4 * h;
            atomicAdd(&pout[(base + q) * DIM + D * 32 + col], O[r]);
        }
    }
    if (h == 0) atomicAdd(&pl[base + col], l);
}

// ---------------- K7: normalize + scatter --------------------------------
__global__ __launch_bounds__(256) void comb_kernel(
    const float* __restrict__ pl, const float* __restrict__ pout,
    const int* __restrict__ sel, float* __restrict__ out) {
    const int idx = blockIdx.x * 256 + threadIdx.x;
    if (idx >= BATCH * LQ * 16) return;
    const int b = idx / (LQ * 16);
    const int r = idx % (LQ * 16);
    const int qs = r >> 4, c = r & 15;
    const size_t s0 = (size_t)b * QPAD + qs;
    const float inv = 1.0f / pl[s0];
    float4 a = ((const float4*)(pout + s0 * DIM))[c];
    float4 o = make_float4(a.x * inv, a.y * inv, a.z * inv, a.w * inv);
    const int row = sel[b * QPAD + qs];
    ((float4*)(out + ((size_t)b * SEQ + row) * DIM))[c] = o;
}

// ---------------- launcher ----------------
extern "C" void kernel_launch(void* const* d_in, const int* in_sizes, int n_in,
                              void* d_out, int out_size, void* d_ws, size_t ws_size,
                              hipStream_t stream) {
    const float* x  = (const float*)d_in[0];
    const float* Wq = (const float*)d_in[1];
    const float* Wk = (const float*)d_in[2];
    const float* Wv = (const float*)d_in[3];
    float* out = (float*)d_out;
    char* wsb  = (char*)d_ws;

    // workspace layout (bytes), total ~29.8 MB
    float*    Q       = (float*)(wsb);                 //  8,388,608
    _Float16* Qh      = (_Float16*)(wsb + 8388608);    //  4,194,304
    _Float16* Kh      = (_Float16*)(wsb + 12582912);   //  4,194,304
    ushort_t* Vt      = (ushort_t*)(wsb + 16777216);   //  4,194,304
    float*    meanacc = (float*)(wsb + 20971520);      //  2,048
    float*    Kred    = (float*)(wsb + 20973568);      //  2,048
    float*    sqk     = (float*)(wsb + 20975616);      //  131,072
    int*      sel     = (int*)(wsb + 21106688);        //  90,112
    // alias region: Kt (8,388,608 fp32) lives here until kmean consumes it;
    // then pout (5,767,168) + pl (90,112) are zeroed into the same region.
    float*    Kt      = (float*)(wsb + 21196800);
    float*    pout    = (float*)(wsb + 21196800);
    float*    pl      = (float*)(wsb + 21196800 + 5767168);

    hipMemsetAsync(meanacc, 0, 512 * sizeof(float), stream);
    proj_kernel  <<<dim3(64, 8),          256, 0, stream>>>(x, Wq, Wk, Wv, Q, Kt,
                                                            Qh, Kh, Vt, meanacc);
    kmean_kernel <<<512,                  256, 0, stream>>>(Kt, Kred);
    sqk_kernel   <<<dim3(16, 8),          256, 0, stream>>>(Q, Kred, sqk);
    select_kernel<<<8,                    256, 0, stream>>>(sqk, sel);
    fill_kernel  <<<2048,                 256, 0, stream>>>(meanacc, out);
    // Kt is dead after kmean; zero the region for the attention atomics.
    hipMemsetAsync(pout, 0, 5767168 + 90112, stream);
    attn_kernel  <<<dim3(NQB, KS, BATCH), 256, 0, stream>>>((const ushort_t*)Qh,
                                                            (const ushort_t*)Kh,
                                                            Vt, sel, pl, pout);
    comb_kernel  <<<1372,                 256, 0, stream>>>(pl, pout, sel, out);
}

// Round 4
// 195.048 us; speedup vs baseline: 3.6963x; 1.0355x over previous
//
#include <hip/hip_runtime.h>
#include <hip/hip_bf16.h>
#include <math.h>

#define BATCH 8
#define SEQ   4096
#define DIM   64
#define LQ    2744            // int((1-0.33)*4096)
#define QPB   128             // queries per attn block
#define NQB   22              // ceil(2744/128)
#define QPAD  2816            // NQB*QPB
#define KS    4               // key splits (1024 keys per block)
#define L2E   1.4426950408889634f
#define QSC   0.1803368801111204f   // 0.125 * log2(e), folded into Qh

typedef _Float16 half8 __attribute__((ext_vector_type(8)));
typedef short    bs8   __attribute__((ext_vector_type(8)));
typedef float    fx16  __attribute__((ext_vector_type(16)));
typedef unsigned short ushort_t;

union UH { uint4 u4; half8 h; };
union UB { unsigned u[4]; uint4 u4; bs8 s; };

__device__ __forceinline__ unsigned pack_bf16(float a, float b) {
    __hip_bfloat162 h = __float22bfloat162_rn(make_float2(a, b));
    union { __hip_bfloat162 h; unsigned u; } cv; cv.h = h; return cv.u;
}

// ---------------- sortable-uint mapping ----------------
__device__ __forceinline__ unsigned f2sort(float f) {
    unsigned u = __float_as_uint(f);
    return (u & 0x80000000u) ? ~u : (u | 0x80000000u);
}
__device__ __forceinline__ float sort2f(unsigned u) {
    return __uint_as_float((u & 0x80000000u) ? (u & 0x7FFFFFFFu) : ~u);
}

// ---------------- radix select, parallel scan (256 threads) --------------
__device__ void radix_select_4096(const unsigned* u, int k, unsigned* hist,
                                  unsigned* scan, unsigned* res) {
    const int t = threadIdx.x;
    if (t == 0) { res[0] = 0u; res[1] = (unsigned)k; }
    for (int pass = 3; pass >= 0; --pass) {
        const int shift = pass * 8;
        hist[t] = 0u;
        __syncthreads();
        const unsigned pref  = res[0];
        const unsigned kk    = res[1];
        const unsigned hmask = (pass == 3) ? 0u : (0xFFFFFFFFu << (shift + 8));
        for (int i = t; i < 4096; i += 256) {
            unsigned ui = u[i];
            if ((ui & hmask) == pref) atomicAdd(&hist[(ui >> shift) & 255u], 1u);
        }
        __syncthreads();
        const unsigned h = hist[t];
        unsigned s = h;
        scan[t] = s;
        __syncthreads();
#pragma unroll
        for (int ofs = 1; ofs < 256; ofs <<= 1) {
            unsigned add = (t + ofs < 256) ? scan[t + ofs] : 0u;
            __syncthreads();
            s += add;
            scan[t] = s;
            __syncthreads();
        }
        if (s >= kk && (s - h) < kk) {   // unique threshold bin
            res[0] = pref | ((unsigned)t << shift);
            res[1] = kk - (s - h);
        }
        __syncthreads();
    }
}

// ---------------- K1: projections -------------------
// Q fp32 (selection), Kt fp32 (channel top-k), Qh f16 scaled, Kh f16,
// Vt bf16 transposed+k-permuted (PV B-fragment order), pmean = per-block
// V column partial sums (no atomics; kmean aggregates).
__global__ __launch_bounds__(256) void proj_kernel(
    const float* __restrict__ x,  const float* __restrict__ Wq,
    const float* __restrict__ Wk, const float* __restrict__ Wv,
    float* __restrict__ Q, float* __restrict__ Kt,
    _Float16* __restrict__ Qh, _Float16* __restrict__ Kh,
    ushort_t* __restrict__ Vt, float* __restrict__ pmean) {
    const int rt = blockIdx.x, b = blockIdx.y, t = threadIdx.x;
    __shared__ float4 xs4[64 * 17];
    __shared__ float  red[4][64];
    {
        const float4* xg = (const float4*)(x + ((size_t)b * SEQ + rt * 64) * DIM);
        for (int i = 0; i < 4; ++i) {
            int s = t + 256 * i;
            xs4[(s >> 4) * 17 + (s & 15)] = xg[s];
        }
    }
    __syncthreads();
    const int ch = t & 63, rg = t >> 6;
    float accq[16], acck[16], accv[16];
#pragma unroll
    for (int i = 0; i < 16; ++i) { accq[i] = 0.f; acck[i] = 0.f; accv[i] = 0.f; }
    for (int dc = 0; dc < 4; ++dc) {
        float wq[16], wk[16], wv[16];
#pragma unroll
        for (int dd = 0; dd < 16; ++dd) {
            int d = dc * 16 + dd;
            wq[dd] = Wq[d * 64 + ch]; wk[dd] = Wk[d * 64 + ch]; wv[dd] = Wv[d * 64 + ch];
        }
        for (int r = 0; r < 16; ++r) {
            const int row = rg * 16 + r;
            const float4* xr = &xs4[row * 17 + dc * 4];
            float xv[16];
            float4 a0 = xr[0], a1 = xr[1], a2 = xr[2], a3 = xr[3];
            xv[0]=a0.x; xv[1]=a0.y; xv[2]=a0.z; xv[3]=a0.w;
            xv[4]=a1.x; xv[5]=a1.y; xv[6]=a1.z; xv[7]=a1.w;
            xv[8]=a2.x; xv[9]=a2.y; xv[10]=a2.z; xv[11]=a2.w;
            xv[12]=a3.x; xv[13]=a3.y; xv[14]=a3.z; xv[15]=a3.w;
#pragma unroll
            for (int dd = 0; dd < 16; ++dd) {
                accq[r] = fmaf(xv[dd], wq[dd], accq[r]);
                acck[r] = fmaf(xv[dd], wk[dd], acck[r]);
                accv[r] = fmaf(xv[dd], wv[dd], accv[r]);
            }
        }
    }
    const int rowbase = rt * 64 + rg * 16;
    float sv = 0.f;
#pragma unroll
    for (int r = 0; r < 16; ++r) {
        size_t o = ((size_t)b * SEQ + rowbase + r) * DIM + ch;
        Q[o]  = accq[r];
        Qh[o] = (_Float16)(accq[r] * QSC);
        Kh[o] = (_Float16)acck[r];
        sv += accv[r];
    }
    float4* ktp = (float4*)(Kt + ((size_t)b * 64 + ch) * SEQ + rowbase);
    ktp[0] = make_float4(acck[0], acck[1], acck[2], acck[3]);
    ktp[1] = make_float4(acck[4], acck[5], acck[6], acck[7]);
    ktp[2] = make_float4(acck[8], acck[9], acck[10], acck[11]);
    ktp[3] = make_float4(acck[12], acck[13], acck[14], acck[15]);
    // Vt bf16, k-permuted pair order within each 16-group: [0,1,4,5,2,3,6,7]
    {
        unsigned pk[8];
#pragma unroll
        for (int i = 0; i < 8; ++i) pk[i] = pack_bf16(accv[2*i], accv[2*i+1]);
        uint4* vp = (uint4*)(Vt + ((size_t)(b * 64 + ch)) * SEQ + rowbase);
        vp[0] = make_uint4(pk[0], pk[1], pk[4], pk[5]);
        vp[1] = make_uint4(pk[2], pk[3], pk[6], pk[7]);
    }
    red[rg][ch] = sv;
    __syncthreads();
    if (rg == 0)
        pmean[((size_t)b * 64 + ch) * 64 + rt] =
            red[0][ch] + red[1][ch] + red[2][ch] + red[3][ch];
}

// ---------------- K2: K_reduce = mean of top-LQ per (b,ch); V-mean agg ---
__global__ __launch_bounds__(256) void kmean_kernel(const float* __restrict__ Kt,
                                                    const float* __restrict__ pmean,
                                                    float* __restrict__ Kred,
                                                    float* __restrict__ meanfin) {
    __shared__ unsigned u[4096];
    __shared__ unsigned hist[256];
    __shared__ unsigned scan[256];
    __shared__ unsigned res[2];
    __shared__ float rsum[4];
    const int bc = blockIdx.x, t = threadIdx.x;
    // V-mean aggregation for this (b,ch): wave 0 sums the 64 partials
    if (t < 64) {
        float v = pmean[(size_t)bc * 64 + t];
        for (int m = 1; m < 64; m <<= 1) v += __shfl_xor(v, m, 64);
        if (t == 0) meanfin[bc] = v * (1.0f / (float)SEQ);
    }
    const float4* c4 = (const float4*)(Kt + (size_t)bc * SEQ);
    for (int i = t; i < 1024; i += 256) {
        float4 v = c4[i];
        u[i*4+0] = f2sort(v.x); u[i*4+1] = f2sort(v.y);
        u[i*4+2] = f2sort(v.z); u[i*4+3] = f2sort(v.w);
    }
    __syncthreads();
    radix_select_4096(u, LQ, hist, scan, res);
    const unsigned Tu = res[0];
    const int krem = (int)res[1];
    float loc = 0.f;
    for (int i = t; i < 4096; i += 256)
        if (u[i] > Tu) loc += sort2f(u[i]);
    for (int msk = 1; msk < 64; msk <<= 1) loc += __shfl_xor(loc, msk, 64);
    if ((t & 63) == 0) rsum[t >> 6] = loc;
    __syncthreads();
    if (t == 0) {
        float s = rsum[0] + rsum[1] + rsum[2] + rsum[3] + (float)krem * sort2f(Tu);
        Kred[bc] = s / (float)LQ;
    }
}

// ---------------- K3: sqk = K_reduce . Q (fp32, selection-exact) ---------
__global__ __launch_bounds__(256) void sqk_kernel(const float* __restrict__ Q,
                                                  const float* __restrict__ Kred,
                                                  float* __restrict__ sqk) {
    const int b = blockIdx.y, l = blockIdx.x * 256 + threadIdx.x;
    __shared__ float kr[64];
    if (threadIdx.x < 64) kr[threadIdx.x] = Kred[b * 64 + threadIdx.x];
    __syncthreads();
    const float4* q = (const float4*)(Q + ((size_t)b * SEQ + l) * DIM);
    float s = 0.f;
#pragma unroll
    for (int i = 0; i < 16; ++i) {
        float4 v = q[i];
        s = fmaf(v.x, kr[i*4+0], s); s = fmaf(v.y, kr[i*4+1], s);
        s = fmaf(v.z, kr[i*4+2], s); s = fmaf(v.w, kr[i*4+3], s);
    }
    sqk[b * SEQ + l] = s;
}

// ---------------- K4: per-batch top-LQ selection + inverse map -----------
__global__ __launch_bounds__(256) void select_kernel(const float* __restrict__ sqk,
                                                     int* __restrict__ sel,
                                                     int* __restrict__ inv) {
    __shared__ unsigned u[4096];
    __shared__ unsigned hist[256];
    __shared__ unsigned scan[256];
    __shared__ unsigned res[2];
    __shared__ int eq_idx[256];
    __shared__ int cnts[2];
    const int b = blockIdx.x, t = threadIdx.x;
    const float* col = sqk + (size_t)b * SEQ;
    int* invb = inv + (size_t)b * SEQ;
    for (int i = t; i < 4096; i += 256) {
        u[i] = f2sort(col[i]);
        invb[i] = -1;
    }
    if (t < 2) cnts[t] = 0;
    __syncthreads();
    radix_select_4096(u, LQ, hist, scan, res);
    const unsigned Tu = res[0];
    const int krem = (int)res[1];
    int* selb = sel + b * QPAD;
    for (int i = t; i < 4096; i += 256) {
        unsigned ui = u[i];
        if (ui > Tu) {
            int p = atomicAdd(&cnts[0], 1);
            selb[p] = i;
            invb[i] = p;
        } else if (ui == Tu) {
            int p = atomicAdd(&cnts[1], 1);
            if (p < 256) eq_idx[p] = i;
        }
    }
    __syncthreads();
    if (t == 0) {
        int ng = cnts[0];
        int ne = cnts[1] < 256 ? cnts[1] : 256;
        for (int i = 1; i < ne; ++i) {          // ties ~unique floats: ne≈1
            int v = eq_idx[i], j = i - 1;
            while (j >= 0 && eq_idx[j] > v) { eq_idx[j+1] = eq_idx[j]; --j; }
            eq_idx[j+1] = v;
        }
        for (int j = 0; j < krem; ++j) {
            selb[ng + j] = eq_idx[j];
            invb[eq_idx[j]] = ng + j;
        }
    }
    __syncthreads();
    if (t < QPAD - LQ) selb[LQ + t] = selb[LQ - 1];   // pad (parallel)
}

// ---------------- K5: MFMA flash attention (no-max online softmax) -------
// KS=4 key splits (grid 704, ~2.75 blocks/CU). Partials are plain sums, so
// key-split merge = global fp32 atomicAdd into zeroed pout/pl.
// __launch_bounds__(256,3): ~168 VGPR cap -> no spills, hoisted addresses.
__global__ __launch_bounds__(256, 3) void attn_kernel(
    const ushort_t* __restrict__ Qh, const ushort_t* __restrict__ Kh,
    const ushort_t* __restrict__ Vt, const int* __restrict__ sel,
    float* __restrict__ pl, float* __restrict__ pout) {
    const int qt = blockIdx.x, ks = blockIdx.y, b = blockIdx.z;
    const int t = threadIdx.x, w = t >> 6, lane = t & 63;
    const int col = lane & 31, h = lane >> 5;

    __shared__ ushort_t Ktile[2][32 * 64];
    __shared__ ushort_t Vtile[2][32 * 64];

    // persistent Q fragments (B-operand: lane holds q=col, d=16m+8h+j)
    half8 qf[4];
    {
        const int q = qt * QPB + w * 32 + col;
        const int row = sel[b * QPAD + q];
        const uint4* qg = (const uint4*)(Qh + ((size_t)b * SEQ + row) * DIM);
#pragma unroll
        for (int m = 0; m < 4; ++m) { UH u; u.u4 = qg[2 * m + h]; qf[m] = u.h; }
    }

    // loop-invariant swizzled LDS offsets (ushort elements)
    int koff[4], voff[4];
#pragma unroll
    for (int m = 0; m < 4; ++m)
        koff[m] = col * 64 + 8 * ((2 * m + h) ^ (col & 7));
#pragma unroll
    for (int i = 0; i < 4; ++i)
        voff[i] = col * 64 + 8 * ((i * 2 + h) ^ (col & 7));  // i = D*2+c -> 4D+2c+h

    fx16 O0, O1;
#pragma unroll
    for (int r = 0; r < 16; ++r) { O0[r] = 0.f; O1[r] = 0.f; }
    float l = 0.f;

    const int srow = t >> 3, sgr = t & 7;
    const int lg = sgr ^ (srow & 7);
    const int vD = lg >> 2, vc = (lg >> 1) & 1, vh = lg & 1;
    const size_t kgbase = ((size_t)b * SEQ + ks * 1024 + srow) * DIM + 8 * lg;
    const size_t vgbase = ((size_t)(b * DIM + srow + 32 * vD)) * SEQ
                          + ks * 1024 + vc * 16 + vh * 8;

    uint4 kreg = *(const uint4*)(Kh + kgbase);
    uint4 vreg = *(const uint4*)(Vt + vgbase);

    for (int tile = 0; tile < 32; ++tile) {
        const int buf = tile & 1;
        *(uint4*)&Ktile[buf][srow * 64 + sgr * 8] = kreg;
        *(uint4*)&Vtile[buf][srow * 64 + sgr * 8] = vreg;
        __syncthreads();
        if (tile < 31) {   // prefetch next tile during compute
            kreg = *(const uint4*)(Kh + kgbase + (size_t)(tile + 1) * 32 * DIM);
            vreg = *(const uint4*)(Vt + vgbase + (size_t)(tile + 1) * 32);
        }
        // S^T = K * Q^T  (f16 MFMA); Qh pre-scaled by 0.125*log2e
        fx16 S;
#pragma unroll
        for (int r = 0; r < 16; ++r) S[r] = 0.f;
#pragma unroll
        for (int m = 0; m < 4; ++m) {
            UH kf;
            kf.u4 = *(const uint4*)&Ktile[buf][koff[m]];
            S = __builtin_amdgcn_mfma_f32_32x32x16_f16(kf.h, qf[m], S, 0, 0, 0);
        }
        // softmax numerators (no max subtraction: scores bounded « 128)
        float p[16];
#pragma unroll
        for (int r = 0; r < 16; ++r) p[r] = exp2f(S[r]);
#pragma unroll
        for (int r = 0; r < 16; ++r) l += p[r];
        UB A0, A1;
#pragma unroll
        for (int v = 0; v < 4; ++v) {
            A0.u[v] = pack_bf16(p[2 * v],     p[2 * v + 1]);
            A1.u[v] = pack_bf16(p[8 + 2 * v], p[8 + 2 * v + 1]);
        }
        // O += P * V  (bf16 MFMA)
#pragma unroll
        for (int D = 0; D < 2; ++D) {
            fx16& O = D ? O1 : O0;
#pragma unroll
            for (int c = 0; c < 2; ++c) {
                UB vf;
                vf.u4 = *(const uint4*)&Vtile[buf][voff[D * 2 + c]];
                O = __builtin_amdgcn_mfma_f32_32x32x16_bf16(c ? A1.s : A0.s, vf.s, O, 0, 0, 0);
            }
        }
    }

    l += __shfl_xor(l, 32);   // combine the two k-halves of the column sum

    const int qg0 = qt * QPB + w * 32;
    const size_t base = (size_t)b * QPAD + qg0;
#pragma unroll
    for (int D = 0; D < 2; ++D) {
        const fx16& O = D ? O1 : O0;
#pragma unroll
        for (int r = 0; r < 16; ++r) {
            const int q = (r & 3) + 8 * (r >> 2) + 4 * h;
            atomicAdd(&pout[(base + q) * DIM + D * 32 + col], O[r]);
        }
    }
    if (h == 0) atomicAdd(&pl[base + col], l);
}

// ---------------- K6: normalize+scatter OR mean-fill, one pass -----------
__global__ __launch_bounds__(256) void comb_kernel(
    const float* __restrict__ pl, const float* __restrict__ pout,
    const int* __restrict__ inv, const float* __restrict__ meanfin,
    float* __restrict__ out) {
    const int idx = blockIdx.x * 256 + threadIdx.x;   // over BATCH*SEQ*16
    const int b = idx >> 16;
    const int rc = idx & 65535;
    const int row = rc >> 4, c = rc & 15;
    const int p = inv[b * SEQ + row];
    float4 o;
    if (p >= 0) {
        const size_t s0 = (size_t)b * QPAD + p;
        const float invl = 1.0f / pl[s0];
        float4 a = ((const float4*)(pout + s0 * DIM))[c];
        o = make_float4(a.x * invl, a.y * invl, a.z * invl, a.w * invl);
    } else {
        o = make_float4(meanfin[b * 64 + c * 4 + 0], meanfin[b * 64 + c * 4 + 1],
                        meanfin[b * 64 + c * 4 + 2], meanfin[b * 64 + c * 4 + 3]);
    }
    ((float4*)out)[idx] = o;
}

// ---------------- launcher ----------------
extern "C" void kernel_launch(void* const* d_in, const int* in_sizes, int n_in,
                              void* d_out, int out_size, void* d_ws, size_t ws_size,
                              hipStream_t stream) {
    const float* x  = (const float*)d_in[0];
    const float* Wq = (const float*)d_in[1];
    const float* Wk = (const float*)d_in[2];
    const float* Wv = (const float*)d_in[3];
    float* out = (float*)d_out;
    char* wsb  = (char*)d_ws;

    // workspace layout (bytes), total ~29.9 MB
    float*    Q       = (float*)(wsb);                 //  8,388,608
    _Float16* Qh      = (_Float16*)(wsb + 8388608);    //  4,194,304
    _Float16* Kh      = (_Float16*)(wsb + 12582912);   //  4,194,304
    ushort_t* Vt      = (ushort_t*)(wsb + 16777216);   //  4,194,304
    float*    pmean   = (float*)(wsb + 20971520);      //  131,072
    float*    meanfin = (float*)(wsb + 21102592);      //  2,048
    float*    Kred    = (float*)(wsb + 21104640);      //  2,048
    float*    sqk     = (float*)(wsb + 21106688);      //  131,072
    int*      sel     = (int*)(wsb + 21237760);        //  90,112
    int*      inv     = (int*)(wsb + 21327872);        //  131,072
    // alias region: Kt (8,388,608) until kmean consumes it; then pout+pl
    float*    Kt      = (float*)(wsb + 21458944);
    float*    pout    = (float*)(wsb + 21458944);      //  5,767,168
    float*    pl      = (float*)(wsb + 21458944 + 5767168);  // 90,112

    proj_kernel  <<<dim3(64, 8),          256, 0, stream>>>(x, Wq, Wk, Wv, Q, Kt,
                                                            Qh, Kh, Vt, pmean);
    kmean_kernel <<<512,                  256, 0, stream>>>(Kt, pmean, Kred, meanfin);
    sqk_kernel   <<<dim3(16, 8),          256, 0, stream>>>(Q, Kred, sqk);
    select_kernel<<<8,                    256, 0, stream>>>(sqk, sel, inv);
    // Kt dead after kmean; zero the region for the attention atomics.
    hipMemsetAsync(pout, 0, 5767168 + 90112, stream);
    attn_kernel  <<<dim3(NQB, KS, BATCH), 256, 0, stream>>>((const ushort_t*)Qh,
                                                            (const ushort_t*)Kh,
                                                            Vt, sel, pl, pout);
    comb_kernel  <<<2048,                 256, 0, stream>>>(pl, pout, inv, meanfin, out);
}